// Round 1
// baseline (92.429 us; speedup 1.0000x reference)
//
#include <hip/hip_runtime.h>
#include <math.h>

#define BB 2
#define SS 512
#define DD 64
#define DDDD 4096   // DD*DD

// -------- Kernel 1: per (b,s) LayerNorm stats + dt + decay a = exp(dt * -exp(log_A)) --------
__global__ __launch_bounds__(256) void k1_stats(
    const float* __restrict__ x, const float* __restrict__ log_A,
    const float* __restrict__ dt_w, const float* __restrict__ dt_b,
    const float* __restrict__ ln_w, const float* __restrict__ ln_b,
    float* __restrict__ a_out, float2* __restrict__ stats)
{
    const int bs  = blockIdx.x;       // b*SS + s, 0..1023
    const int tid = threadIdx.x;      // 256 threads, each owns 16 contiguous elems

    const float4* xp4 = (const float4*)(x + (size_t)bs * DDDD + tid * 16);
    float4 v0 = xp4[0], v1 = xp4[1], v2 = xp4[2], v3 = xp4[3];

    float sum = (v0.x+v0.y+v0.z+v0.w) + (v1.x+v1.y+v1.z+v1.w)
              + (v2.x+v2.y+v2.z+v2.w) + (v3.x+v3.y+v3.z+v3.w);
    float sq  = (v0.x*v0.x+v0.y*v0.y+v0.z*v0.z+v0.w*v0.w)
              + (v1.x*v1.x+v1.y*v1.y+v1.z*v1.z+v1.w*v1.w)
              + (v2.x*v2.x+v2.y*v2.y+v2.z*v2.z+v2.w*v2.w)
              + (v3.x*v3.x+v3.y*v3.y+v3.z*v3.z+v3.w*v3.w);

    // wave (64-lane) reduce, then cross-wave via LDS
    #pragma unroll
    for (int off = 32; off > 0; off >>= 1) {
        sum += __shfl_down(sum, off);
        sq  += __shfl_down(sq,  off);
    }
    __shared__ float s_sum[4], s_sq[4];
    const int wv = tid >> 6, ln = tid & 63;
    if (ln == 0) { s_sum[wv] = sum; s_sq[wv] = sq; }
    __syncthreads();
    const float tsum = s_sum[0] + s_sum[1] + s_sum[2] + s_sum[3];
    const float tsq  = s_sq[0]  + s_sq[1]  + s_sq[2]  + s_sq[3];
    const float mu   = tsum * (1.0f / DDDD);
    const float var  = tsq  * (1.0f / DDDD) - mu * mu;
    const float rstd = rsqrtf(var + 1e-5f);

    // dt dot: thread's 16 elems are row d = tid>>2, cols c0 = (tid&3)*16 .. +15
    const float4* lw4 = (const float4*)(ln_w + tid * 16);
    const float4* lb4 = (const float4*)(ln_b + tid * 16);
    const float4* dw4 = (const float4*)(dt_w + (tid & 3) * 16);
    float p = 0.f;
    #define ACC4(vv, ii) { \
        float4 lw = lw4[ii], lb = lb4[ii], dw = dw4[ii];            \
        p = fmaf(fmaf((vv.x - mu) * rstd, lw.x, lb.x), dw.x, p);    \
        p = fmaf(fmaf((vv.y - mu) * rstd, lw.y, lb.y), dw.y, p);    \
        p = fmaf(fmaf((vv.z - mu) * rstd, lw.z, lb.z), dw.z, p);    \
        p = fmaf(fmaf((vv.w - mu) * rstd, lw.w, lb.w), dw.w, p);    \
    }
    ACC4(v0, 0); ACC4(v1, 1); ACC4(v2, 2); ACC4(v3, 3);
    #undef ACC4

    // reduce the 4 partials per row (lanes are consecutive within a wave)
    p += __shfl_xor(p, 1);
    p += __shfl_xor(p, 2);

    if ((tid & 3) == 0) {
        const int d = tid >> 2;
        float z = p + dt_b[0];
        float dt = (z > 20.f) ? z : log1pf(expf(z));   // softplus
        float la = dt * (-expf(log_A[d]));             // <= 0 always
        a_out[bs * DD + d] = expf(la);                 // decay in (0,1]
    }
    if (tid == 0) stats[bs] = make_float2(mu, rstd);
}

// -------- Kernel 2: chunked scan over t for each (b,r); 8 waves = 8 t-chunks --------
#define NW 8
#define CH (SS / NW)   // 64

__global__ __launch_bounds__(512) void k2_scan(
    const float* __restrict__ x, const float* __restrict__ a_in,
    const float* __restrict__ ln_w, const float* __restrict__ ln_b,
    const float2* __restrict__ stats, float* __restrict__ out)
{
    const int br  = blockIdx.x;            // b*DD + r
    const int b   = br >> 6, r = br & 63;
    const int tid = threadIdx.x;
    const int w   = tid >> 6;              // wave = t-chunk
    const int c   = tid & 63;              // lane = column

    const float lnw = ln_w[r * DD + c];
    const float lnb = ln_b[r * DD + c];

    const int t0 = w * CH;
    const size_t xbase = ((size_t)(b * SS) * DD + r) * DD + c;
    const float*  xp = x   + xbase + (size_t)t0 * DDDD;
    const float*  ap = a_in + (b * SS + t0) * DD + r;
    const float2* sp = stats + b * SS + t0;

    // ---- Phase 1: local scan (final state + decay product only) ----
    float state = 0.f, P = 1.f;
    for (int t = 0; t < CH; t += 8) {
        float xv[8], av[8]; float2 st[8];
        #pragma unroll
        for (int i = 0; i < 8; ++i) {
            xv[i] = xp[(size_t)(t + i) * DDDD];
            av[i] = ap[(t + i) * DD];
            st[i] = sp[t + i];
        }
        #pragma unroll
        for (int i = 0; i < 8; ++i) {
            float xn = fmaf((xv[i] - st[i].x) * st[i].y, lnw, lnb);
            state = fmaf(av[i], state, xn);
            P *= av[i];
        }
    }

    __shared__ float sF[NW][DD];
    __shared__ float sP[NW];
    sF[w][c] = state;
    if (c == 0) sP[w] = P;
    __syncthreads();

    // carry entering this wave's chunk = combined state of all earlier chunks
    float carry = 0.f;
    for (int v = 0; v < w; ++v) carry = fmaf(sP[v], carry, sF[v][c]);

    // ---- Phase 2: rescan with carry, write output ----
    state = carry;
    float* op = out + xbase + (size_t)t0 * DDDD;
    for (int t = 0; t < CH; t += 8) {
        float xv[8], av[8]; float2 st[8];
        #pragma unroll
        for (int i = 0; i < 8; ++i) {
            xv[i] = xp[(size_t)(t + i) * DDDD];
            av[i] = ap[(t + i) * DD];
            st[i] = sp[t + i];
        }
        #pragma unroll
        for (int i = 0; i < 8; ++i) {
            float xn = fmaf((xv[i] - st[i].x) * st[i].y, lnw, lnb);
            state = fmaf(av[i], state, xn);
            op[(size_t)(t + i) * DDDD] = state + xv[i];
        }
    }
}

extern "C" void kernel_launch(void* const* d_in, const int* in_sizes, int n_in,
                              void* d_out, int out_size, void* d_ws, size_t ws_size,
                              hipStream_t stream) {
    const float* x     = (const float*)d_in[0];
    const float* log_A = (const float*)d_in[1];
    const float* dt_w  = (const float*)d_in[2];
    const float* dt_b  = (const float*)d_in[3];
    const float* ln_w  = (const float*)d_in[4];
    const float* ln_b  = (const float*)d_in[5];
    float* out = (float*)d_out;

    float*  a_buf = (float*)d_ws;                                          // B*S*D floats
    float2* stats = (float2*)((char*)d_ws + (size_t)BB * SS * DD * sizeof(float)); // B*S float2

    k1_stats<<<BB * SS, 256, 0, stream>>>(x, log_A, dt_w, dt_b, ln_w, ln_b, a_buf, stats);
    k2_scan<<<BB * DD, 512, 0, stream>>>(x, a_buf, ln_w, ln_b, stats, out);
}

// Round 4
// 89.879 us; speedup vs baseline: 1.0284x; 1.0284x over previous
//
#include <hip/hip_runtime.h>
#include <math.h>

#define BB 2
#define SS 512
#define DD 64
#define DDDD 4096   // DD*DD
#define NC 16       // time chunks
#define CL (SS / NC) // 32 chunk length

// -------- Kernel 1: per (b,s) LayerNorm stats + dt + decay a = exp(dt * -exp(log_A)) --------
__global__ __launch_bounds__(256) void k1_stats(
    const float* __restrict__ x, const float* __restrict__ log_A,
    const float* __restrict__ dt_w, const float* __restrict__ dt_b,
    const float* __restrict__ ln_w, const float* __restrict__ ln_b,
    float* __restrict__ a_out, float2* __restrict__ stats)
{
    const int bs  = blockIdx.x;       // b*SS + s, 0..1023
    const int tid = threadIdx.x;      // 256 threads, each owns 16 contiguous elems

    const float4* xp4 = (const float4*)(x + (size_t)bs * DDDD + tid * 16);
    float4 v0 = xp4[0], v1 = xp4[1], v2 = xp4[2], v3 = xp4[3];

    float sum = (v0.x+v0.y+v0.z+v0.w) + (v1.x+v1.y+v1.z+v1.w)
              + (v2.x+v2.y+v2.z+v2.w) + (v3.x+v3.y+v3.z+v3.w);
    float sq  = (v0.x*v0.x+v0.y*v0.y+v0.z*v0.z+v0.w*v0.w)
              + (v1.x*v1.x+v1.y*v1.y+v1.z*v1.z+v1.w*v1.w)
              + (v2.x*v2.x+v2.y*v2.y+v2.z*v2.z+v2.w*v2.w)
              + (v3.x*v3.x+v3.y*v3.y+v3.z*v3.z+v3.w*v3.w);

    #pragma unroll
    for (int off = 32; off > 0; off >>= 1) {
        sum += __shfl_down(sum, off);
        sq  += __shfl_down(sq,  off);
    }
    __shared__ float s_sum[4], s_sq[4];
    const int wv = tid >> 6, ln = tid & 63;
    if (ln == 0) { s_sum[wv] = sum; s_sq[wv] = sq; }
    __syncthreads();
    const float tsum = s_sum[0] + s_sum[1] + s_sum[2] + s_sum[3];
    const float tsq  = s_sq[0]  + s_sq[1]  + s_sq[2]  + s_sq[3];
    const float mu   = tsum * (1.0f / DDDD);
    const float var  = tsq  * (1.0f / DDDD) - mu * mu;
    const float rstd = rsqrtf(var + 1e-5f);

    const float4* lw4 = (const float4*)(ln_w + tid * 16);
    const float4* lb4 = (const float4*)(ln_b + tid * 16);
    const float4* dw4 = (const float4*)(dt_w + (tid & 3) * 16);
    float p = 0.f;
    #define ACC4(vv, ii) { \
        float4 lw = lw4[ii], lb = lb4[ii], dw = dw4[ii];            \
        p = fmaf(fmaf((vv.x - mu) * rstd, lw.x, lb.x), dw.x, p);    \
        p = fmaf(fmaf((vv.y - mu) * rstd, lw.y, lb.y), dw.y, p);    \
        p = fmaf(fmaf((vv.z - mu) * rstd, lw.z, lb.z), dw.z, p);    \
        p = fmaf(fmaf((vv.w - mu) * rstd, lw.w, lb.w), dw.w, p);    \
    }
    ACC4(v0, 0); ACC4(v1, 1); ACC4(v2, 2); ACC4(v3, 3);
    #undef ACC4

    p += __shfl_xor(p, 1);
    p += __shfl_xor(p, 2);

    if ((tid & 3) == 0) {
        const int d = tid >> 2;
        float z = p + dt_b[0];
        float dt = (z > 20.f) ? z : log1pf(expf(z));   // softplus
        float la = dt * (-expf(log_A[d]));             // <= 0 always
        a_out[bs * DD + d] = expf(la);                 // decay in (0,1]
    }
    if (tid == 0) stats[bs] = make_float2(mu, rstd);
}

// -------- Kernel 2a: per (b,r,chunk) local scan -> (F[c], P) --------
// wave gw = br*NC + ch ; lane = column c
__global__ __launch_bounds__(256) void k2a_partial(
    const float* __restrict__ x, const float* __restrict__ a_in,
    const float* __restrict__ ln_w, const float* __restrict__ ln_b,
    const float2* __restrict__ stats,
    float* __restrict__ Fbuf, float* __restrict__ Pbuf)
{
    const int gw = blockIdx.x * 4 + (threadIdx.x >> 6);   // 0..BB*DD*NC-1
    const int c  = threadIdx.x & 63;
    const int ch = gw & (NC - 1);
    const int br = gw >> 4;                               // log2(NC)=4
    const int b  = br >> 6, r = br & 63;

    const float lnw = ln_w[r * DD + c];
    const float lnb = ln_b[r * DD + c];

    const int t0 = ch * CL;
    const float*  xp = x + (((size_t)(b * SS + t0)) * DD + r) * DD + c;
    const float*  ap = a_in + (b * SS + t0) * DD + r;
    const float2* sp = stats + b * SS + t0;

    float state = 0.f, P = 1.f;
    for (int t = 0; t < CL; t += 8) {
        float xv[8], av[8]; float2 st[8];
        #pragma unroll
        for (int i = 0; i < 8; ++i) {
            xv[i] = xp[(size_t)(t + i) * DDDD];
            av[i] = ap[(t + i) * DD];
            st[i] = sp[t + i];
        }
        #pragma unroll
        for (int i = 0; i < 8; ++i) {
            float xn = fmaf((xv[i] - st[i].x) * st[i].y, lnw, lnb);
            state = fmaf(av[i], state, xn);
            P *= av[i];
        }
    }
    Fbuf[(size_t)gw * DD + c] = state;
    if (c == 0) Pbuf[gw] = P;
}

// -------- Kernel 2b: carry from all earlier chunks, rescan, write out --------
__global__ __launch_bounds__(256) void k2b_final(
    const float* __restrict__ x, const float* __restrict__ a_in,
    const float* __restrict__ ln_w, const float* __restrict__ ln_b,
    const float2* __restrict__ stats,
    const float* __restrict__ Fbuf, const float* __restrict__ Pbuf,
    float* __restrict__ out)
{
    const int gw = blockIdx.x * 4 + (threadIdx.x >> 6);
    const int c  = threadIdx.x & 63;
    const int ch = gw & (NC - 1);
    const int br = gw >> 4;
    const int b  = br >> 6, r = br & 63;

    // ---- carry: all NC loads issued up front (independent), masked FMA chain ----
    float f[NC], p[NC];
    #pragma unroll
    for (int v = 0; v < NC; ++v) {
        f[v] = Fbuf[(size_t)(br * NC + v) * DD + c];
        p[v] = Pbuf[br * NC + v];
    }
    float carry = 0.f;
    #pragma unroll
    for (int v = 0; v < NC; ++v) {
        float pv = (v < ch) ? p[v] : 1.f;
        float fv = (v < ch) ? f[v] : 0.f;
        carry = fmaf(pv, carry, fv);
    }

    const float lnw = ln_w[r * DD + c];
    const float lnb = ln_b[r * DD + c];

    const int t0 = ch * CL;
    const size_t xoff = (((size_t)(b * SS + t0)) * DD + r) * DD + c;
    const float*  xp = x + xoff;
    const float*  ap = a_in + (b * SS + t0) * DD + r;
    const float2* sp = stats + b * SS + t0;
    float* op = out + xoff;

    float state = carry;
    for (int t = 0; t < CL; t += 8) {
        float xv[8], av[8]; float2 st[8];
        #pragma unroll
        for (int i = 0; i < 8; ++i) {
            xv[i] = xp[(size_t)(t + i) * DDDD];
            av[i] = ap[(t + i) * DD];
            st[i] = sp[t + i];
        }
        #pragma unroll
        for (int i = 0; i < 8; ++i) {
            float xn = fmaf((xv[i] - st[i].x) * st[i].y, lnw, lnb);
            state = fmaf(av[i], state, xn);
            op[(size_t)(t + i) * DDDD] = state + xv[i];
        }
    }
}

extern "C" void kernel_launch(void* const* d_in, const int* in_sizes, int n_in,
                              void* d_out, int out_size, void* d_ws, size_t ws_size,
                              hipStream_t stream) {
    const float* x     = (const float*)d_in[0];
    const float* log_A = (const float*)d_in[1];
    const float* dt_w  = (const float*)d_in[2];
    const float* dt_b  = (const float*)d_in[3];
    const float* ln_w  = (const float*)d_in[4];
    const float* ln_b  = (const float*)d_in[5];
    float* out = (float*)d_out;

    char* ws = (char*)d_ws;
    float*  a_buf = (float*)ws;                                   // B*S*D floats   (256 KB)
    float2* stats = (float2*)(ws + 262144);                       // B*S float2    (8 KB)
    float*  Fbuf  = (float*)(ws + 262144 + 8192);                 // B*D*NC*DD     (512 KB)
    float*  Pbuf  = (float*)(ws + 262144 + 8192 + 524288);        // B*D*NC        (8 KB)

    k1_stats<<<BB * SS, 256, 0, stream>>>(x, log_A, dt_w, dt_b, ln_w, ln_b, a_buf, stats);
    k2a_partial<<<BB * DD * NC / 4, 256, 0, stream>>>(x, a_buf, ln_w, ln_b, stats, Fbuf, Pbuf);
    k2b_final<<<BB * DD * NC / 4, 256, 0, stream>>>(x, a_buf, ln_w, ln_b, stats, Fbuf, Pbuf, out);
}